// Round 15
// baseline (1245.692 us; speedup 1.0000x reference)
//
#include <hip/hip_runtime.h>

#define BATCH   16384
#define IN_DIM  1024
#define OUT_DIM 4096
#define K_TOP   409
#define NB_CAP  128

typedef _Float16 half8  __attribute__((ext_vector_type(8)));
typedef _Float16 half4v __attribute__((ext_vector_type(4)));
typedef float    f32x4  __attribute__((ext_vector_type(4)));

// ---------------------------------------------------------------- kernel A
__global__ __launch_bounds__(256)
void k_hasneg(const float* __restrict__ x, int n, int* __restrict__ flag) {
    const int stride = gridDim.x * blockDim.x;
    bool neg = false;
    for (int i = blockIdx.x * blockDim.x + threadIdx.x; i < n; i += stride)
        neg |= (x[i] < 0.0f);
    unsigned long long b = __ballot(neg);
    if (b != 0ULL && (threadIdx.x & 63) == 0)
        atomicOr(flag, 1);
}

// ---------------------------------------------------------------- kernel B
// FAST approximate projected = f16(x)·f16(w)^T, f32 MFMA accumulate.
// |fast-exact| <~ 2.3e-3 worst-case; k_select's exact-chain replica recovers
// bit-exact selection. 128x128 tile, BK=64, 4 waves (2x2), 4x4 16x16x32
// fragments per wave. Reg-prefetch double-buffer (T14): issue tile t+1's
// global loads before tile t's MFMA, convert+ds_write after the barrier.
// LDS f16 tiles XOR-swizzled at 16B slots (slot ^= row&7): conflict-free
// ds_read_b128. XCD-aware block swizzle (T1) for w-panel L2 locality.
__global__ __launch_bounds__(256)
void k_gemm(const float* __restrict__ x, const float* __restrict__ w,
            float* __restrict__ out, const int* __restrict__ flag) {
    __shared__ _Float16 Ah[128 * 64];
    __shared__ _Float16 Bh[128 * 64];
    const int tid = threadIdx.x;
    const int bid = blockIdx.x;                  // 4096 blocks, %8==0
    const int swz = (bid & 7) * 512 + (bid >> 3);
    const int bm = swz & 127, bn = swz >> 7;
    const bool bipolar = (*flag == 0);
    const int lane = tid & 63;
    const int wv = tid >> 6;
    const int wm = wv >> 1, wn = wv & 1;
    const int lr = lane & 15, lk = lane >> 4;

    const int sr = tid >> 1;                     // staging row 0..127
    const int sc = (tid & 1) * 32;               // staging col half
    const float* xr = x + (size_t)(bm * 128 + sr) * IN_DIM;
    const float* wrow = w + (size_t)(bn * 128 + sr) * IN_DIM;

    f32x4 acc[4][4] = {};
    float4 pa[8], pb[8];

    // prologue: load + stage tile 0
    #pragma unroll
    for (int i = 0; i < 8; ++i) {
        pa[i] = *(const float4*)&xr[sc + i * 4];
        pb[i] = *(const float4*)&wrow[sc + i * 4];
    }
    #pragma unroll
    for (int i = 0; i < 8; ++i) {
        const int c = sc + i * 4;
        const int off = sr * 64 + ((((c >> 3) ^ (sr & 7))) << 3) + (c & 7);
        float4 v = pa[i];
        if (bipolar) {
            v.x = (v.x - 0.5f) * 2.0f; v.y = (v.y - 0.5f) * 2.0f;
            v.z = (v.z - 0.5f) * 2.0f; v.w = (v.w - 0.5f) * 2.0f;
        }
        *(half4v*)&Ah[off] = half4v{ (_Float16)v.x, (_Float16)v.y,
                                     (_Float16)v.z, (_Float16)v.w };
        float4 u = pb[i];
        *(half4v*)&Bh[off] = half4v{ (_Float16)u.x, (_Float16)u.y,
                                     (_Float16)u.z, (_Float16)u.w };
    }
    __syncthreads();

    #pragma unroll 1
    for (int t = 0; t < 16; ++t) {
        if (t < 15) {                            // issue next-tile loads EARLY
            #pragma unroll
            for (int i = 0; i < 8; ++i) {
                pa[i] = *(const float4*)&xr[(t + 1) * 64 + sc + i * 4];
                pb[i] = *(const float4*)&wrow[(t + 1) * 64 + sc + i * 4];
            }
        }
        #pragma unroll
        for (int h = 0; h < 2; ++h) {            // two K=32 steps
            half8 af[4], bf[4];
            #pragma unroll
            for (int i = 0; i < 4; ++i) {
                const int ra = wm * 64 + i * 16 + lr;
                const int sa = (h * 4 + lk) ^ (ra & 7);
                af[i] = *(const half8*)&Ah[ra * 64 + (sa << 3)];
                const int rb = wn * 64 + i * 16 + lr;
                const int sb = (h * 4 + lk) ^ (rb & 7);
                bf[i] = *(const half8*)&Bh[rb * 64 + (sb << 3)];
            }
            #pragma unroll
            for (int i = 0; i < 4; ++i)
                #pragma unroll
                for (int j = 0; j < 4; ++j)
                    acc[i][j] = __builtin_amdgcn_mfma_f32_16x16x32_f16(
                        af[i], bf[j], acc[i][j], 0, 0, 0);
        }
        __syncthreads();                         // done reading tile t
        if (t < 15) {                            // convert + write tile t+1
            #pragma unroll
            for (int i = 0; i < 8; ++i) {
                const int c = sc + i * 4;
                const int off = sr * 64 + ((((c >> 3) ^ (sr & 7))) << 3) + (c & 7);
                float4 v = pa[i];
                if (bipolar) {
                    v.x = (v.x - 0.5f) * 2.0f; v.y = (v.y - 0.5f) * 2.0f;
                    v.z = (v.z - 0.5f) * 2.0f; v.w = (v.w - 0.5f) * 2.0f;
                }
                *(half4v*)&Ah[off] = half4v{ (_Float16)v.x, (_Float16)v.y,
                                             (_Float16)v.z, (_Float16)v.w };
                float4 u = pb[i];
                *(half4v*)&Bh[off] = half4v{ (_Float16)u.x, (_Float16)u.y,
                                             (_Float16)u.z, (_Float16)u.w };
            }
            __syncthreads();                     // tile t+1 ready
        }
    }
    // epilogue: C/D layout col=lane&15, row=(lane>>4)*4+q
    #pragma unroll
    for (int i = 0; i < 4; ++i)
        #pragma unroll
        for (int j = 0; j < 4; ++j)
            #pragma unroll
            for (int q = 0; q < 4; ++q) {
                const int row = bm * 128 + wm * 64 + i * 16 + lk * 4 + q;
                const int col = bn * 128 + wn * 64 + j * 16 + lr;
                out[(size_t)row * OUT_DIM + col] = acc[i][j][q];
            }
}

// ---------------------------------------------------------------- kernel C
// one block per row. Single-pass 1024-bucket LINEAR histogram of positives
// locates the bucket of the K-th largest fast value (no exact radix select
// needed -- the borderline replica only requires a window guaranteed to
// contain the boundary). Window = bucket +- 8e-3 (effective delta = bucketw
// + 8e-3 > 2*e_max). Window recomputed with the EXACT reference chain
// (r13-proven: single accumulator, ascending-k __fmaf_rn); select window
// members by replica value, >=-tie-inclusive. relu, L2 normalize, in place.
__global__ __launch_bounds__(256)
void k_select(float* __restrict__ po, const float* __restrict__ x,
              const float* __restrict__ w, const int* __restrict__ flag) {
    __shared__ float sv[OUT_DIM];            // 16 KB: fast values
    __shared__ unsigned int bins[1024];      // 4 KB: linear histogram
    __shared__ float xs[IN_DIM];             // 4 KB: exact x_bipolar row
    __shared__ float fred[4];
    __shared__ unsigned int wsum[4];
    __shared__ int s_bstar;
    __shared__ unsigned int s_hi, s_nb;
    __shared__ int bl_idx[NB_CAP];
    __shared__ float bl_np[NB_CAP];
    __shared__ unsigned char bl_in[NB_CAP];

    const int row = blockIdx.x;
    const int tid = threadIdx.x;
    float* prow = po + (size_t)row * OUT_DIM;

    float vmax = -1e30f;
    for (int j = tid; j < OUT_DIM; j += 256) {
        float v = prow[j];
        sv[j] = v;
        vmax = fmaxf(vmax, v);
    }
    #pragma unroll
    for (int off = 32; off > 0; off >>= 1)
        vmax = fmaxf(vmax, __shfl_down(vmax, off));
    if ((tid & 63) == 0) fred[tid >> 6] = vmax;
    bins[tid] = 0; bins[tid + 256] = 0; bins[tid + 512] = 0; bins[tid + 768] = 0;
    if (tid == 0) { s_hi = 0; s_nb = 0; s_bstar = 0; }
    __syncthreads();
    vmax = fmaxf(fmaxf(fred[0], fred[1]), fmaxf(fred[2], fred[3]));
    vmax = fmaxf(vmax, 1e-6f);
    const float scale = 1024.0f / vmax;
    const float invscale = vmax * (1.0f / 1024.0f);

    // single histogram pass (positives only; values spread -> few conflicts)
    for (int j = tid; j < OUT_DIM; j += 256) {
        float v = sv[j];
        if (v > 0.0f) {
            int b = (int)(v * scale);
            if (b > 1023) b = 1023;
            atomicAdd(&bins[b], 1u);
        }
    }
    __syncthreads();

    // top-down scan over 256 groups of 4 buckets -> bucket of K-th largest
    const int g = 255 - tid;                 // descending groups
    const unsigned int c = bins[4 * g] + bins[4 * g + 1]
                         + bins[4 * g + 2] + bins[4 * g + 3];
    unsigned int sc = c;
    #pragma unroll
    for (int off = 1; off < 64; off <<= 1) {
        unsigned int t2 = __shfl_up(sc, off);
        if ((tid & 63) >= off) sc += t2;
    }
    if ((tid & 63) == 63) wsum[tid >> 6] = sc;
    __syncthreads();
    for (int wq = 0; wq < (tid >> 6); ++wq) sc += wsum[wq];
    if ((int)sc >= K_TOP && (int)(sc - c) < K_TOP) {
        int cum = (int)(sc - c);
        int bstar = 4 * g;
        for (int bi = 4 * g + 3; bi >= 4 * g; --bi) {
            cum += (int)bins[bi];
            if (cum >= K_TOP) { bstar = bi; break; }
        }
        s_bstar = bstar;
    }
    __syncthreads();
    const float delta = 8e-3f;
    const float thi = (float)(s_bstar + 1) * invscale + delta;
    const float tlo = (float)s_bstar * invscale - delta;

    // classify: certainly-in vs borderline window
    for (int j = tid; j < OUT_DIM; j += 256) {
        float v = sv[j];
        if (v > thi) atomicAdd(&s_hi, 1u);
        else if (v >= tlo) {
            unsigned int p = atomicAdd(&s_nb, 1u);
            if (p < NB_CAP) bl_idx[p] = j;
        }
    }
    __syncthreads();
    const int hi = (int)s_hi;
    int nb = (int)s_nb; if (nb > NB_CAP) nb = NB_CAP;
    int krem = K_TOP - hi; if (krem > nb) krem = nb; if (krem < 0) krem = 0;
    const bool need = (nb != krem);

    if (need) {
        const bool bipolar = (*flag == 0);
        for (int i = tid; i < IN_DIM; i += 256) {
            float xv = x[(size_t)row * IN_DIM + i];
            xs[i] = bipolar ? __fmul_rn(__fadd_rn(xv, -0.5f), 2.0f) : xv;
        }
        __syncthreads();
        // EXACT reference chain (bitwise r13): single acc, ascending k, FMA.
        for (int m = tid; m < nb; m += 256) {
            const float* wr = w + (size_t)bl_idx[m] * IN_DIM;
            float p = 0.0f;
            for (int i = 0; i < IN_DIM; ++i)
                p = __fmaf_rn(xs[i], wr[i], p);
            bl_np[m] = p;
        }
        __syncthreads();
        if (tid == 0) {
            for (int m = 0; m < nb; ++m) bl_in[m] = 0;
            if (krem > 0) {
                float thr_b = 1e30f;
                for (int it = 0; it < krem; ++it) {
                    int best = -1; float bv = -1e30f;
                    for (int m = 0; m < nb; ++m)
                        if (!bl_in[m] && bl_np[m] > bv) { bv = bl_np[m]; best = m; }
                    if (best >= 0) { bl_in[best] = 1; thr_b = bv; }
                }
                // >=-tie semantics (reference keeps K+1 on exact ties)
                for (int m = 0; m < nb; ++m)
                    bl_in[m] = (bl_np[m] >= thr_b) ? 1 : 0;
            }
        }
        __syncthreads();
    }

    // encode = relu * mask, norm, write normalized in place
    float nrm2 = 0.0f;
    for (int j = tid; j < OUT_DIM; j += 256) {
        float v = sv[j];
        bool sel = false;
        float val = v;
        if (v > thi) sel = true;
        else if (v >= tlo) {
            if (!need) sel = true;
            else {
                for (int m = 0; m < nb; ++m)
                    if (bl_idx[m] == j) {
                        sel = (bl_in[m] != 0);
                        val = bl_np[m];       // exact reference value
                        break;
                    }
            }
        }
        float e = (sel && val > 0.0f) ? val : 0.0f;
        sv[j] = e;
        nrm2 += e * e;
    }
    #pragma unroll
    for (int off = 32; off > 0; off >>= 1)
        nrm2 += __shfl_down(nrm2, off);
    if ((tid & 63) == 0) fred[tid >> 6] = nrm2;
    __syncthreads();
    const float total = fred[0] + fred[1] + fred[2] + fred[3];
    const float inv = 1.0f / fmaxf(sqrtf(total), 1e-12f);
    for (int j = tid; j < OUT_DIM; j += 256) prow[j] = sv[j] * inv;
}

// ---------------------------------------------------------------- launch
extern "C" void kernel_launch(void* const* d_in, const int* in_sizes, int n_in,
                              void* d_out, int out_size, void* d_ws, size_t ws_size,
                              hipStream_t stream) {
    const float* x = (const float*)d_in[0];
    const float* w = (const float*)d_in[1];
    float* out = (float*)d_out;
    int* flag = (int*)d_ws;

    hipMemsetAsync(flag, 0, sizeof(int), stream);
    k_hasneg<<<2048, 256, 0, stream>>>(x, BATCH * IN_DIM, flag);

    k_gemm<<<4096, 256, 0, stream>>>(x, w, out, flag);

    k_select<<<BATCH, 256, 0, stream>>>(out, x, w, flag);
}

// Round 16
// 914.934 us; speedup vs baseline: 1.3615x; 1.3615x over previous
//
#include <hip/hip_runtime.h>

#define BATCH   16384
#define IN_DIM  1024
#define OUT_DIM 4096
#define K_TOP   409
#define NB_CAP  128

typedef _Float16 half8  __attribute__((ext_vector_type(8)));
typedef _Float16 half4v __attribute__((ext_vector_type(4)));
typedef float    f32x4  __attribute__((ext_vector_type(4)));

// workspace layout: [0..4) flag | [256 ..) x_h (16M f16) | then w_h (4M f16)
#define WS_XH_OFF   256
#define WS_WH_OFF   (WS_XH_OFF + (size_t)BATCH * IN_DIM * 2)
#define WS_NEEDED   (WS_WH_OFF + (size_t)OUT_DIM * IN_DIM * 2)

// ---------------------------------------------------------------- kernel A
__global__ __launch_bounds__(256)
void k_hasneg(const float* __restrict__ x, int n, int* __restrict__ flag) {
    const int stride = gridDim.x * blockDim.x;
    bool neg = false;
    for (int i = blockIdx.x * blockDim.x + threadIdx.x; i < n; i += stride)
        neg |= (x[i] < 0.0f);
    unsigned long long b = __ballot(neg);
    if (b != 0ULL && (threadIdx.x & 63) == 0)
        atomicOr(flag, 1);
}

// ---------------------------------------------------------------- kernel A2
// one-time f32 -> f16 conversion: x_h = f16(bipolar(x)), w_h = f16(w).
__global__ __launch_bounds__(256)
void k_cvt(const float* __restrict__ x, const float* __restrict__ w,
           _Float16* __restrict__ xh, _Float16* __restrict__ wh,
           const int* __restrict__ flag) {
    const bool bipolar = (*flag == 0);
    const int stride = gridDim.x * blockDim.x;
    const int nx4 = BATCH * IN_DIM / 4;
    const int nw4 = OUT_DIM * IN_DIM / 4;
    for (int i = blockIdx.x * blockDim.x + threadIdx.x; i < nx4; i += stride) {
        float4 v = ((const float4*)x)[i];
        if (bipolar) {
            v.x = (v.x - 0.5f) * 2.0f; v.y = (v.y - 0.5f) * 2.0f;
            v.z = (v.z - 0.5f) * 2.0f; v.w = (v.w - 0.5f) * 2.0f;
        }
        ((half4v*)xh)[i] = half4v{ (_Float16)v.x, (_Float16)v.y,
                                   (_Float16)v.z, (_Float16)v.w };
    }
    for (int i = blockIdx.x * blockDim.x + threadIdx.x; i < nw4; i += stride) {
        float4 u = ((const float4*)w)[i];
        ((half4v*)wh)[i] = half4v{ (_Float16)u.x, (_Float16)u.y,
                                   (_Float16)u.z, (_Float16)u.w };
    }
}

// ---------------------------------------------------------------- kernel B
// FAST projected = f16(x)·f16(w)^T via MFMA, m97 structure:
// 128x128 tile, BK=64, global_load_lds width 16 (no VGPR round-trip, no
// convert on the critical path). LDS XOR-swizzle (16B slot ^= row&7) kept
// by PRE-SWIZZLING the per-lane GLOBAL source (linear LDS dest, m173
// pattern): src_slot = (l&7) ^ ((l>>3)&7), constant per lane. Fragment
// ds_read_b128 pattern identical to r15 (measured 0 bank conflicts).
__global__ __launch_bounds__(256)
void k_gemm16(const _Float16* __restrict__ xh, const _Float16* __restrict__ wh,
              float* __restrict__ out) {
    __shared__ _Float16 Ah[128 * 64];
    __shared__ _Float16 Bh[128 * 64];
    const int tid = threadIdx.x;
    const int bm = blockIdx.x, bn = blockIdx.y;
    const int lane = tid & 63;
    const int wv = tid >> 6;
    const int wm = wv >> 1, wn = wv & 1;
    const int lr = lane & 15, lk = lane >> 4;

    // staging geometry: per wave-issue, 64 lanes x 16B = 1KB = 8 rows.
    const int srow = (lane >> 3);                 // 0..7 within issue
    const int sslot = (lane & 7) ^ srow;          // pre-swizzled source slot
    f32x4 acc[4][4] = {};

    const _Float16* aS[4]; const _Float16* bS[4];
    _Float16* aD[4]; _Float16* bD[4];
    #pragma unroll
    for (int i = 0; i < 4; ++i) {
        const int rb = i * 32 + wv * 8;           // row base of this issue
        aS[i] = xh + (size_t)(bm * 128 + rb + srow) * IN_DIM + sslot * 8;
        bS[i] = wh + (size_t)(bn * 128 + rb + srow) * IN_DIM + sslot * 8;
        aD[i] = &Ah[rb * 64];
        bD[i] = &Bh[rb * 64];
    }

    #pragma unroll 1
    for (int kt = 0; kt < IN_DIM; kt += 64) {
        __syncthreads();                          // readers of prev tile done
        #pragma unroll
        for (int i = 0; i < 4; ++i) {
            __builtin_amdgcn_global_load_lds((const __attribute__((address_space(1))) void*)(aS[i] + kt), (__attribute__((address_space(3))) void*)aD[i], 16, 0, 0);
            __builtin_amdgcn_global_load_lds((const __attribute__((address_space(1))) void*)(bS[i] + kt), (__attribute__((address_space(3))) void*)bD[i], 16, 0, 0);
        }
        __syncthreads();                          // vmcnt drained: tile ready
        #pragma unroll
        for (int h = 0; h < 2; ++h) {
            half8 af[4], bf[4];
            #pragma unroll
            for (int i = 0; i < 4; ++i) {
                const int ra = wm * 64 + i * 16 + lr;
                const int sa = (h * 4 + lk) ^ (ra & 7);
                af[i] = *(const half8*)&Ah[ra * 64 + (sa << 3)];
                const int rb = wn * 64 + i * 16 + lr;
                const int sb = (h * 4 + lk) ^ (rb & 7);
                bf[i] = *(const half8*)&Bh[rb * 64 + (sb << 3)];
            }
            #pragma unroll
            for (int i = 0; i < 4; ++i)
                #pragma unroll
                for (int j = 0; j < 4; ++j)
                    acc[i][j] = __builtin_amdgcn_mfma_f32_16x16x32_f16(
                        af[i], bf[j], acc[i][j], 0, 0, 0);
        }
    }
    #pragma unroll
    for (int i = 0; i < 4; ++i)
        #pragma unroll
        for (int j = 0; j < 4; ++j)
            #pragma unroll
            for (int q = 0; q < 4; ++q) {
                const int row = bm * 128 + wm * 64 + i * 16 + lk * 4 + q;
                const int col = bn * 128 + wn * 64 + j * 16 + lr;
                out[(size_t)row * OUT_DIM + col] = acc[i][j][q];
            }
}

// ---------------------------------------------------------------- kernel B'
// fallback when ws_size too small: r14-style (inline convert, reg dbuf).
__global__ __launch_bounds__(256)
void k_gemm_fb(const float* __restrict__ x, const float* __restrict__ w,
               float* __restrict__ out, const int* __restrict__ flag) {
    __shared__ _Float16 Ah[128 * 64];
    __shared__ _Float16 Bh[128 * 64];
    const int tid = threadIdx.x;
    const int bm = blockIdx.x, bn = blockIdx.y;
    const bool bipolar = (*flag == 0);
    const int lane = tid & 63;
    const int wv = tid >> 6;
    const int wm = wv >> 1, wn = wv & 1;
    const int lr = lane & 15, lk = lane >> 4;
    const int sr = tid >> 1;
    const int sc = (tid & 1) * 32;
    const float* xr = x + (size_t)(bm * 128 + sr) * IN_DIM;
    const float* wrow = w + (size_t)(bn * 128 + sr) * IN_DIM;
    f32x4 acc[4][4] = {};
    #pragma unroll 1
    for (int kt = 0; kt < IN_DIM; kt += 64) {
        __syncthreads();
        #pragma unroll
        for (int i = 0; i < 8; ++i) {
            const int c = sc + i * 4;
            const int off = sr * 64 + ((((c >> 3) ^ (sr & 7))) << 3) + (c & 7);
            float4 v = *(const float4*)&xr[kt + c];
            if (bipolar) {
                v.x = (v.x - 0.5f) * 2.0f; v.y = (v.y - 0.5f) * 2.0f;
                v.z = (v.z - 0.5f) * 2.0f; v.w = (v.w - 0.5f) * 2.0f;
            }
            *(half4v*)&Ah[off] = half4v{ (_Float16)v.x, (_Float16)v.y,
                                         (_Float16)v.z, (_Float16)v.w };
            float4 u = *(const float4*)&wrow[kt + c];
            *(half4v*)&Bh[off] = half4v{ (_Float16)u.x, (_Float16)u.y,
                                         (_Float16)u.z, (_Float16)u.w };
        }
        __syncthreads();
        #pragma unroll
        for (int h = 0; h < 2; ++h) {
            half8 af[4], bf[4];
            #pragma unroll
            for (int i = 0; i < 4; ++i) {
                const int ra = wm * 64 + i * 16 + lr;
                const int sa = (h * 4 + lk) ^ (ra & 7);
                af[i] = *(const half8*)&Ah[ra * 64 + (sa << 3)];
                const int rb = wn * 64 + i * 16 + lr;
                const int sb = (h * 4 + lk) ^ (rb & 7);
                bf[i] = *(const half8*)&Bh[rb * 64 + (sb << 3)];
            }
            #pragma unroll
            for (int i = 0; i < 4; ++i)
                #pragma unroll
                for (int j = 0; j < 4; ++j)
                    acc[i][j] = __builtin_amdgcn_mfma_f32_16x16x32_f16(
                        af[i], bf[j], acc[i][j], 0, 0, 0);
        }
    }
    #pragma unroll
    for (int i = 0; i < 4; ++i)
        #pragma unroll
        for (int j = 0; j < 4; ++j)
            #pragma unroll
            for (int q = 0; q < 4; ++q) {
                const int row = bm * 128 + wm * 64 + i * 16 + lk * 4 + q;
                const int col = bn * 128 + wn * 64 + j * 16 + lr;
                out[(size_t)row * OUT_DIM + col] = acc[i][j][q];
            }
}

// ---------------------------------------------------------------- kernel C
// one block per row: 1024-bucket linear histogram locates the K-th fast
// value's bucket; window = bucket +- 8e-3; window recomputed with the EXACT
// reference chain (r13-proven: single acc, ascending-k __fmaf_rn) using
// float4 batched loads (chain order preserved, loads pipelined); select
// window members by replica value, >=-tie-inclusive. relu, L2 norm, in place.
__global__ __launch_bounds__(256)
void k_select(float* __restrict__ po, const float* __restrict__ x,
              const float* __restrict__ w, const int* __restrict__ flag) {
    __shared__ float sv[OUT_DIM];
    __shared__ unsigned int bins[1024];
    __shared__ float xs[IN_DIM];
    __shared__ float fred[4];
    __shared__ unsigned int wsum[4];
    __shared__ int s_bstar;
    __shared__ unsigned int s_hi, s_nb;
    __shared__ int bl_idx[NB_CAP];
    __shared__ float bl_np[NB_CAP];
    __shared__ unsigned char bl_in[NB_CAP];

    const int row = blockIdx.x;
    const int tid = threadIdx.x;
    float* prow = po + (size_t)row * OUT_DIM;

    float vmax = -1e30f;
    for (int j = tid; j < OUT_DIM; j += 256) {
        float v = prow[j];
        sv[j] = v;
        vmax = fmaxf(vmax, v);
    }
    #pragma unroll
    for (int off = 32; off > 0; off >>= 1)
        vmax = fmaxf(vmax, __shfl_down(vmax, off));
    if ((tid & 63) == 0) fred[tid >> 6] = vmax;
    bins[tid] = 0; bins[tid + 256] = 0; bins[tid + 512] = 0; bins[tid + 768] = 0;
    if (tid == 0) { s_hi = 0; s_nb = 0; s_bstar = 0; }
    __syncthreads();
    vmax = fmaxf(fmaxf(fred[0], fred[1]), fmaxf(fred[2], fred[3]));
    vmax = fmaxf(vmax, 1e-6f);
    const float scale = 1024.0f / vmax;
    const float invscale = vmax * (1.0f / 1024.0f);

    for (int j = tid; j < OUT_DIM; j += 256) {
        float v = sv[j];
        if (v > 0.0f) {
            int b = (int)(v * scale);
            if (b > 1023) b = 1023;
            atomicAdd(&bins[b], 1u);
        }
    }
    __syncthreads();

    const int g = 255 - tid;
    const unsigned int c = bins[4 * g] + bins[4 * g + 1]
                         + bins[4 * g + 2] + bins[4 * g + 3];
    unsigned int sc = c;
    #pragma unroll
    for (int off = 1; off < 64; off <<= 1) {
        unsigned int t2 = __shfl_up(sc, off);
        if ((tid & 63) >= off) sc += t2;
    }
    if ((tid & 63) == 63) wsum[tid >> 6] = sc;
    __syncthreads();
    for (int wq = 0; wq < (tid >> 6); ++wq) sc += wsum[wq];
    if ((int)sc >= K_TOP && (int)(sc - c) < K_TOP) {
        int cum = (int)(sc - c);
        int bstar = 4 * g;
        for (int bi = 4 * g + 3; bi >= 4 * g; --bi) {
            cum += (int)bins[bi];
            if (cum >= K_TOP) { bstar = bi; break; }
        }
        s_bstar = bstar;
    }
    __syncthreads();
    const float delta = 8e-3f;
    const float thi = (float)(s_bstar + 1) * invscale + delta;
    const float tlo = (float)s_bstar * invscale - delta;

    for (int j = tid; j < OUT_DIM; j += 256) {
        float v = sv[j];
        if (v > thi) atomicAdd(&s_hi, 1u);
        else if (v >= tlo) {
            unsigned int p = atomicAdd(&s_nb, 1u);
            if (p < NB_CAP) bl_idx[p] = j;
        }
    }
    __syncthreads();
    const int hi = (int)s_hi;
    int nb = (int)s_nb; if (nb > NB_CAP) nb = NB_CAP;
    int krem = K_TOP - hi; if (krem > nb) krem = nb; if (krem < 0) krem = 0;
    const bool need = (nb != krem);

    if (need) {
        const bool bipolar = (*flag == 0);
        for (int i = tid; i < IN_DIM; i += 256) {
            float xv = x[(size_t)row * IN_DIM + i];
            xs[i] = bipolar ? __fmul_rn(__fadd_rn(xv, -0.5f), 2.0f) : xv;
        }
        __syncthreads();
        // EXACT reference chain, float4-batched (order preserved, loads
        // pipeline ahead of the dependent FMA chain).
        for (int m = tid; m < nb; m += 256) {
            const float4* wr4 = (const float4*)(w + (size_t)bl_idx[m] * IN_DIM);
            const float4* xs4 = (const float4*)xs;
            float p = 0.0f;
            #pragma unroll 4
            for (int i = 0; i < IN_DIM / 4; ++i) {
                float4 wv = wr4[i];
                float4 xv = xs4[i];
                p = __fmaf_rn(xv.x, wv.x, p);
                p = __fmaf_rn(xv.y, wv.y, p);
                p = __fmaf_rn(xv.z, wv.z, p);
                p = __fmaf_rn(xv.w, wv.w, p);
            }
            bl_np[m] = p;
        }
        __syncthreads();
        if (tid == 0) {
            for (int m = 0; m < nb; ++m) bl_in[m] = 0;
            if (krem > 0) {
                float thr_b = 1e30f;
                for (int it = 0; it < krem; ++it) {
                    int best = -1; float bv = -1e30f;
                    for (int m = 0; m < nb; ++m)
                        if (!bl_in[m] && bl_np[m] > bv) { bv = bl_np[m]; best = m; }
                    if (best >= 0) { bl_in[best] = 1; thr_b = bv; }
                }
                for (int m = 0; m < nb; ++m)
                    bl_in[m] = (bl_np[m] >= thr_b) ? 1 : 0;
            }
        }
        __syncthreads();
    }

    float nrm2 = 0.0f;
    for (int j = tid; j < OUT_DIM; j += 256) {
        float v = sv[j];
        bool sel = false;
        float val = v;
        if (v > thi) sel = true;
        else if (v >= tlo) {
            if (!need) sel = true;
            else {
                for (int m = 0; m < nb; ++m)
                    if (bl_idx[m] == j) {
                        sel = (bl_in[m] != 0);
                        val = bl_np[m];
                        break;
                    }
            }
        }
        float e = (sel && val > 0.0f) ? val : 0.0f;
        sv[j] = e;
        nrm2 += e * e;
    }
    #pragma unroll
    for (int off = 32; off > 0; off >>= 1)
        nrm2 += __shfl_down(nrm2, off);
    if ((tid & 63) == 0) fred[tid >> 6] = nrm2;
    __syncthreads();
    const float total = fred[0] + fred[1] + fred[2] + fred[3];
    const float inv = 1.0f / fmaxf(sqrtf(total), 1e-12f);
    for (int j = tid; j < OUT_DIM; j += 256) prow[j] = sv[j] * inv;
}

// ---------------------------------------------------------------- launch
extern "C" void kernel_launch(void* const* d_in, const int* in_sizes, int n_in,
                              void* d_out, int out_size, void* d_ws, size_t ws_size,
                              hipStream_t stream) {
    const float* x = (const float*)d_in[0];
    const float* w = (const float*)d_in[1];
    float* out = (float*)d_out;
    int* flag = (int*)d_ws;

    hipMemsetAsync(flag, 0, sizeof(int), stream);
    k_hasneg<<<2048, 256, 0, stream>>>(x, BATCH * IN_DIM, flag);

    dim3 g(BATCH / 128, OUT_DIM / 128);
    if (ws_size >= WS_NEEDED) {
        _Float16* xh = (_Float16*)((char*)d_ws + WS_XH_OFF);
        _Float16* wh = (_Float16*)((char*)d_ws + WS_WH_OFF);
        k_cvt<<<2048, 256, 0, stream>>>(x, w, xh, wh, flag);
        k_gemm16<<<g, 256, 0, stream>>>(xh, wh, out);
    } else {
        k_gemm_fb<<<g, 256, 0, stream>>>(x, w, out, flag);
    }

    k_select<<<BATCH, 256, 0, stream>>>(out, x, w, flag);
}

// Round 17
// 829.028 us; speedup vs baseline: 1.5026x; 1.1036x over previous
//
#include <hip/hip_runtime.h>

#define BATCH   16384
#define IN_DIM  1024
#define OUT_DIM 4096
#define K_TOP   409
#define NB_CAP  128

typedef _Float16 half8  __attribute__((ext_vector_type(8)));
typedef _Float16 half4v __attribute__((ext_vector_type(4)));
typedef float    f32x4  __attribute__((ext_vector_type(4)));

// workspace layout: [0..4) flag | [256 ..) x_h (16M f16) | then w_h (4M f16)
#define WS_XH_OFF   256
#define WS_WH_OFF   (WS_XH_OFF + (size_t)BATCH * IN_DIM * 2)
#define WS_NEEDED   (WS_WH_OFF + (size_t)OUT_DIM * IN_DIM * 2)

// ---------------------------------------------------------------- kernel A
__global__ __launch_bounds__(256)
void k_hasneg(const float* __restrict__ x, int n, int* __restrict__ flag) {
    const int stride = gridDim.x * blockDim.x;
    bool neg = false;
    for (int i = blockIdx.x * blockDim.x + threadIdx.x; i < n; i += stride)
        neg |= (x[i] < 0.0f);
    unsigned long long b = __ballot(neg);
    if (b != 0ULL && (threadIdx.x & 63) == 0)
        atomicOr(flag, 1);
}

// ---------------------------------------------------------------- kernel A2
__global__ __launch_bounds__(256)
void k_cvt(const float* __restrict__ x, const float* __restrict__ w,
           _Float16* __restrict__ xh, _Float16* __restrict__ wh,
           const int* __restrict__ flag) {
    const bool bipolar = (*flag == 0);
    const int stride = gridDim.x * blockDim.x;
    const int nx4 = BATCH * IN_DIM / 4;
    const int nw4 = OUT_DIM * IN_DIM / 4;
    for (int i = blockIdx.x * blockDim.x + threadIdx.x; i < nx4; i += stride) {
        float4 v = ((const float4*)x)[i];
        if (bipolar) {
            v.x = (v.x - 0.5f) * 2.0f; v.y = (v.y - 0.5f) * 2.0f;
            v.z = (v.z - 0.5f) * 2.0f; v.w = (v.w - 0.5f) * 2.0f;
        }
        ((half4v*)xh)[i] = half4v{ (_Float16)v.x, (_Float16)v.y,
                                   (_Float16)v.z, (_Float16)v.w };
    }
    for (int i = blockIdx.x * blockDim.x + threadIdx.x; i < nw4; i += stride) {
        float4 u = ((const float4*)w)[i];
        ((half4v*)wh)[i] = half4v{ (_Float16)u.x, (_Float16)u.y,
                                   (_Float16)u.z, (_Float16)u.w };
    }
}

// ---------------------------------------------------------------- kernel B
// (unchanged from r16: global_load_lds w16, pre-swizzled source, 0 conflicts)
__global__ __launch_bounds__(256)
void k_gemm16(const _Float16* __restrict__ xh, const _Float16* __restrict__ wh,
              float* __restrict__ out) {
    __shared__ _Float16 Ah[128 * 64];
    __shared__ _Float16 Bh[128 * 64];
    const int tid = threadIdx.x;
    const int bm = blockIdx.x, bn = blockIdx.y;
    const int lane = tid & 63;
    const int wv = tid >> 6;
    const int wm = wv >> 1, wn = wv & 1;
    const int lr = lane & 15, lk = lane >> 4;

    const int srow = (lane >> 3);
    const int sslot = (lane & 7) ^ srow;
    f32x4 acc[4][4] = {};

    const _Float16* aS[4]; const _Float16* bS[4];
    _Float16* aD[4]; _Float16* bD[4];
    #pragma unroll
    for (int i = 0; i < 4; ++i) {
        const int rb = i * 32 + wv * 8;
        aS[i] = xh + (size_t)(bm * 128 + rb + srow) * IN_DIM + sslot * 8;
        bS[i] = wh + (size_t)(bn * 128 + rb + srow) * IN_DIM + sslot * 8;
        aD[i] = &Ah[rb * 64];
        bD[i] = &Bh[rb * 64];
    }

    #pragma unroll 1
    for (int kt = 0; kt < IN_DIM; kt += 64) {
        __syncthreads();
        #pragma unroll
        for (int i = 0; i < 4; ++i) {
            __builtin_amdgcn_global_load_lds((const __attribute__((address_space(1))) void*)(aS[i] + kt), (__attribute__((address_space(3))) void*)aD[i], 16, 0, 0);
            __builtin_amdgcn_global_load_lds((const __attribute__((address_space(1))) void*)(bS[i] + kt), (__attribute__((address_space(3))) void*)bD[i], 16, 0, 0);
        }
        __syncthreads();
        #pragma unroll
        for (int h = 0; h < 2; ++h) {
            half8 af[4], bf[4];
            #pragma unroll
            for (int i = 0; i < 4; ++i) {
                const int ra = wm * 64 + i * 16 + lr;
                const int sa = (h * 4 + lk) ^ (ra & 7);
                af[i] = *(const half8*)&Ah[ra * 64 + (sa << 3)];
                const int rb = wn * 64 + i * 16 + lr;
                const int sb = (h * 4 + lk) ^ (rb & 7);
                bf[i] = *(const half8*)&Bh[rb * 64 + (sb << 3)];
            }
            #pragma unroll
            for (int i = 0; i < 4; ++i)
                #pragma unroll
                for (int j = 0; j < 4; ++j)
                    acc[i][j] = __builtin_amdgcn_mfma_f32_16x16x32_f16(
                        af[i], bf[j], acc[i][j], 0, 0, 0);
        }
    }
    #pragma unroll
    for (int i = 0; i < 4; ++i)
        #pragma unroll
        for (int j = 0; j < 4; ++j)
            #pragma unroll
            for (int q = 0; q < 4; ++q) {
                const int row = bm * 128 + wm * 64 + i * 16 + lk * 4 + q;
                const int col = bn * 128 + wn * 64 + j * 16 + lr;
                out[(size_t)row * OUT_DIM + col] = acc[i][j][q];
            }
}

// ---------------------------------------------------------------- kernel B'
__global__ __launch_bounds__(256)
void k_gemm_fb(const float* __restrict__ x, const float* __restrict__ w,
               float* __restrict__ out, const int* __restrict__ flag) {
    __shared__ _Float16 Ah[128 * 64];
    __shared__ _Float16 Bh[128 * 64];
    const int tid = threadIdx.x;
    const int bm = blockIdx.x, bn = blockIdx.y;
    const bool bipolar = (*flag == 0);
    const int lane = tid & 63;
    const int wv = tid >> 6;
    const int wm = wv >> 1, wn = wv & 1;
    const int lr = lane & 15, lk = lane >> 4;
    const int sr = tid >> 1;
    const int sc = (tid & 1) * 32;
    const float* xr = x + (size_t)(bm * 128 + sr) * IN_DIM;
    const float* wrow = w + (size_t)(bn * 128 + sr) * IN_DIM;
    f32x4 acc[4][4] = {};
    #pragma unroll 1
    for (int kt = 0; kt < IN_DIM; kt += 64) {
        __syncthreads();
        #pragma unroll
        for (int i = 0; i < 8; ++i) {
            const int c = sc + i * 4;
            const int off = sr * 64 + ((((c >> 3) ^ (sr & 7))) << 3) + (c & 7);
            float4 v = *(const float4*)&xr[kt + c];
            if (bipolar) {
                v.x = (v.x - 0.5f) * 2.0f; v.y = (v.y - 0.5f) * 2.0f;
                v.z = (v.z - 0.5f) * 2.0f; v.w = (v.w - 0.5f) * 2.0f;
            }
            *(half4v*)&Ah[off] = half4v{ (_Float16)v.x, (_Float16)v.y,
                                         (_Float16)v.z, (_Float16)v.w };
            float4 u = *(const float4*)&wrow[kt + c];
            *(half4v*)&Bh[off] = half4v{ (_Float16)u.x, (_Float16)u.y,
                                         (_Float16)u.z, (_Float16)u.w };
        }
        __syncthreads();
        #pragma unroll
        for (int h = 0; h < 2; ++h) {
            half8 af[4], bf[4];
            #pragma unroll
            for (int i = 0; i < 4; ++i) {
                const int ra = wm * 64 + i * 16 + lr;
                const int sa = (h * 4 + lk) ^ (ra & 7);
                af[i] = *(const half8*)&Ah[ra * 64 + (sa << 3)];
                const int rb = wn * 64 + i * 16 + lr;
                const int sb = (h * 4 + lk) ^ (rb & 7);
                bf[i] = *(const half8*)&Bh[rb * 64 + (sb << 3)];
            }
            #pragma unroll
            for (int i = 0; i < 4; ++i)
                #pragma unroll
                for (int j = 0; j < 4; ++j)
                    acc[i][j] = __builtin_amdgcn_mfma_f32_16x16x32_f16(
                        af[i], bf[j], acc[i][j], 0, 0, 0);
        }
    }
    #pragma unroll
    for (int i = 0; i < 4; ++i)
        #pragma unroll
        for (int j = 0; j < 4; ++j)
            #pragma unroll
            for (int q = 0; q < 4; ++q) {
                const int row = bm * 128 + wm * 64 + i * 16 + lk * 4 + q;
                const int col = bn * 128 + wn * 64 + j * 16 + lr;
                out[(size_t)row * OUT_DIM + col] = acc[i][j][q];
            }
}

// ---------------------------------------------------------------- kernel C
// one block per row. float4-vectorized I/O; histogram locates K-th bucket;
// window = bucket +- 8e-3; replica = EXACT r13 chain (single acc, ascending
// k, __fmaf_rn) with 2-stage register double-buffered loads (latency hidden,
// order unchanged); PARALLEL rank: sel(m) <=> #{l: np[l] > np[m]} < krem
// (provably == ">= krem-th largest", tie-inclusive). relu, L2 norm, in place.
__global__ __launch_bounds__(256)
void k_select(float* __restrict__ po, const float* __restrict__ x,
              const float* __restrict__ w, const int* __restrict__ flag) {
    __shared__ float sv[OUT_DIM];
    __shared__ unsigned int bins[1024];
    __shared__ float xs[IN_DIM];
    __shared__ float fred[4];
    __shared__ unsigned int wsum[4];
    __shared__ int s_bstar;
    __shared__ unsigned int s_hi, s_nb;
    __shared__ int bl_idx[NB_CAP];
    __shared__ float bl_np[NB_CAP];
    __shared__ unsigned char bl_in[NB_CAP];

    const int row = blockIdx.x;
    const int tid = threadIdx.x;
    float* prow = po + (size_t)row * OUT_DIM;

    float vmax = -1e30f;
    #pragma unroll
    for (int it = 0; it < 4; ++it) {
        const int j4 = tid + it * 256;
        float4 v = ((const float4*)prow)[j4];
        ((float4*)sv)[j4] = v;
        vmax = fmaxf(fmaxf(fmaxf(vmax, v.x), fmaxf(v.y, v.z)), v.w);
    }
    #pragma unroll
    for (int off = 32; off > 0; off >>= 1)
        vmax = fmaxf(vmax, __shfl_down(vmax, off));
    if ((tid & 63) == 0) fred[tid >> 6] = vmax;
    bins[tid] = 0; bins[tid + 256] = 0; bins[tid + 512] = 0; bins[tid + 768] = 0;
    if (tid == 0) { s_hi = 0; s_nb = 0; s_bstar = 0; }
    __syncthreads();
    vmax = fmaxf(fmaxf(fred[0], fred[1]), fmaxf(fred[2], fred[3]));
    vmax = fmaxf(vmax, 1e-6f);
    const float scale = 1024.0f / vmax;
    const float invscale = vmax * (1.0f / 1024.0f);

    #pragma unroll
    for (int it = 0; it < 4; ++it) {
        float4 v = ((const float4*)sv)[tid + it * 256];
        #pragma unroll
        for (int e = 0; e < 4; ++e) {
            float f = (e == 0) ? v.x : (e == 1) ? v.y : (e == 2) ? v.z : v.w;
            if (f > 0.0f) {
                int b = (int)(f * scale);
                if (b > 1023) b = 1023;
                atomicAdd(&bins[b], 1u);
            }
        }
    }
    __syncthreads();

    const int g = 255 - tid;
    const unsigned int c = bins[4 * g] + bins[4 * g + 1]
                         + bins[4 * g + 2] + bins[4 * g + 3];
    unsigned int sc = c;
    #pragma unroll
    for (int off = 1; off < 64; off <<= 1) {
        unsigned int t2 = __shfl_up(sc, off);
        if ((tid & 63) >= off) sc += t2;
    }
    if ((tid & 63) == 63) wsum[tid >> 6] = sc;
    __syncthreads();
    for (int wq = 0; wq < (tid >> 6); ++wq) sc += wsum[wq];
    if ((int)sc >= K_TOP && (int)(sc - c) < K_TOP) {
        int cum = (int)(sc - c);
        int bstar = 4 * g;
        for (int bi = 4 * g + 3; bi >= 4 * g; --bi) {
            cum += (int)bins[bi];
            if (cum >= K_TOP) { bstar = bi; break; }
        }
        s_bstar = bstar;
    }
    __syncthreads();
    const float delta = 8e-3f;
    const float thi = (float)(s_bstar + 1) * invscale + delta;
    const float tlo = (float)s_bstar * invscale - delta;

    for (int j = tid; j < OUT_DIM; j += 256) {
        float v = sv[j];
        if (v > thi) atomicAdd(&s_hi, 1u);
        else if (v >= tlo) {
            unsigned int p = atomicAdd(&s_nb, 1u);
            if (p < NB_CAP) bl_idx[p] = j;
        }
    }
    __syncthreads();
    const int hi = (int)s_hi;
    int nb = (int)s_nb; if (nb > NB_CAP) nb = NB_CAP;
    int krem = K_TOP - hi; if (krem > nb) krem = nb; if (krem < 0) krem = 0;
    const bool need = (nb != krem);

    if (need) {
        const bool bipolar = (*flag == 0);
        #pragma unroll
        for (int it = 0; it < 1; ++it) {
            const int i4 = tid;                      // 256 float4 = 1024 elems
            float4 xv = ((const float4*)(x + (size_t)row * IN_DIM))[i4];
            if (bipolar) {
                xv.x = __fmul_rn(__fadd_rn(xv.x, -0.5f), 2.0f);
                xv.y = __fmul_rn(__fadd_rn(xv.y, -0.5f), 2.0f);
                xv.z = __fmul_rn(__fadd_rn(xv.z, -0.5f), 2.0f);
                xv.w = __fmul_rn(__fadd_rn(xv.w, -0.5f), 2.0f);
            }
            ((float4*)xs)[i4] = xv;
        }
        __syncthreads();
        // EXACT reference chain, 2-stage register double-buffered loads.
        // Arithmetic order identical to r13 (ascending k, single acc).
        for (int m = tid; m < nb; m += 256) {
            const float4* wr4 = (const float4*)(w + (size_t)bl_idx[m] * IN_DIM);
            const float4* xs4 = (const float4*)xs;
            float4 bA[8], bB[8];
            #pragma unroll
            for (int u = 0; u < 8; ++u) bA[u] = wr4[u];
            float p = 0.0f;
            #pragma unroll 1
            for (int gg = 0; gg < 16; ++gg) {
                #pragma unroll
                for (int u = 0; u < 8; ++u) bB[u] = wr4[(2 * gg + 1) * 8 + u];
                #pragma unroll
                for (int u = 0; u < 8; ++u) {
                    float4 xv = xs4[(2 * gg) * 8 + u];
                    p = __fmaf_rn(xv.x, bA[u].x, p);
                    p = __fmaf_rn(xv.y, bA[u].y, p);
                    p = __fmaf_rn(xv.z, bA[u].z, p);
                    p = __fmaf_rn(xv.w, bA[u].w, p);
                }
                if (gg < 15) {
                    #pragma unroll
                    for (int u = 0; u < 8; ++u) bA[u] = wr4[(2 * gg + 2) * 8 + u];
                }
                #pragma unroll
                for (int u = 0; u < 8; ++u) {
                    float4 xv = xs4[(2 * gg + 1) * 8 + u];
                    p = __fmaf_rn(xv.x, bB[u].x, p);
                    p = __fmaf_rn(xv.y, bB[u].y, p);
                    p = __fmaf_rn(xv.z, bB[u].z, p);
                    p = __fmaf_rn(xv.w, bB[u].w, p);
                }
            }
            bl_np[m] = p;
        }
        __syncthreads();
        // PARALLEL rank: sel(m) <=> strictly-greater-count < krem.
        for (int m = tid; m < nb; m += 256) {
            if (krem <= 0) { bl_in[m] = 0; continue; }
            const float v = bl_np[m];
            int gcount = 0;
            for (int l = 0; l < nb; ++l) gcount += (bl_np[l] > v);
            bl_in[m] = (gcount < krem) ? 1 : 0;
        }
        __syncthreads();
    }

    float nrm2 = 0.0f;
    for (int j = tid; j < OUT_DIM; j += 256) {
        float v = sv[j];
        bool sel = false;
        float val = v;
        if (v > thi) sel = true;
        else if (v >= tlo) {
            if (!need) sel = true;
            else {
                for (int m = 0; m < nb; ++m)
                    if (bl_idx[m] == j) {
                        sel = (bl_in[m] != 0);
                        val = bl_np[m];
                        break;
                    }
            }
        }
        float e = (sel && val > 0.0f) ? val : 0.0f;
        sv[j] = e;
        nrm2 += e * e;
    }
    #pragma unroll
    for (int off = 32; off > 0; off >>= 1)
        nrm2 += __shfl_down(nrm2, off);
    if ((tid & 63) == 0) fred[tid >> 6] = nrm2;
    __syncthreads();
    const float total = fred[0] + fred[1] + fred[2] + fred[3];
    const float inv = 1.0f / fmaxf(sqrtf(total), 1e-12f);
    #pragma unroll
    for (int it = 0; it < 4; ++it) {
        const int j4 = tid + it * 256;
        float4 e = ((const float4*)sv)[j4];
        e.x *= inv; e.y *= inv; e.z *= inv; e.w *= inv;
        ((float4*)prow)[j4] = e;
    }
}

// ---------------------------------------------------------------- launch
extern "C" void kernel_launch(void* const* d_in, const int* in_sizes, int n_in,
                              void* d_out, int out_size, void* d_ws, size_t ws_size,
                              hipStream_t stream) {
    const float* x = (const float*)d_in[0];
    const float* w = (const float*)d_in[1];
    float* out = (float*)d_out;
    int* flag = (int*)d_ws;

    hipMemsetAsync(flag, 0, sizeof(int), stream);
    k_hasneg<<<2048, 256, 0, stream>>>(x, BATCH * IN_DIM, flag);

    dim3 g(BATCH / 128, OUT_DIM / 128);
    if (ws_size >= WS_NEEDED) {
        _Float16* xh = (_Float16*)((char*)d_ws + WS_XH_OFF);
        _Float16* wh = (_Float16*)((char*)d_ws + WS_WH_OFF);
        k_cvt<<<2048, 256, 0, stream>>>(x, w, xh, wh, flag);
        k_gemm16<<<g, 256, 0, stream>>>(xh, wh, out);
    } else {
        k_gemm_fb<<<g, 256, 0, stream>>>(x, w, out, flag);
    }

    k_select<<<BATCH, 256, 0, stream>>>(out, x, w, flag);
}